// Round 3
// baseline (232.580 us; speedup 1.0000x reference)
//
#include <hip/hip_runtime.h>
#include <cstddef>

#define NB 64
#define NP 1024
#define NPTS (NB * NP)

typedef __attribute__((ext_vector_type(8))) short v8s;
typedef __attribute__((ext_vector_type(4))) float f32x4;

__device__ __forceinline__ float dist2(const float4 pi, const float sqi, const float4 pq) {
    const float dot = fmaf(pi.z, pq.z, fmaf(pi.y, pq.y, pi.x * pq.x));
    return fmaf(-2.0f, dot, sqi + pq.w);
}

__device__ __forceinline__ void pack8(const float* w, v8s& hv, v8s& lv) {
    union { v8s v; unsigned int u[4]; } H, L;
#pragma unroll
    for (int p = 0; p < 4; ++p) {
        unsigned int a = __float_as_uint(w[2 * p]);
        unsigned int b = __float_as_uint(w[2 * p + 1]);
        unsigned int ha = a & 0xffff0000u, hb = b & 0xffff0000u;
        H.u[p] = (ha >> 16) | hb;
        float la = w[2 * p] - __uint_as_float(ha);
        float lb = w[2 * p + 1] - __uint_as_float(hb);
        L.u[p] = (__float_as_uint(la) >> 16) | (__float_as_uint(lb) & 0xffff0000u);
    }
    hv = H.v; lv = L.v;
}

// ---- shared helpers for the edge kernels ----------------------------------

template <int PT, int KP, int KREAL>
__device__ __forceinline__ void load_vrows(const float* __restrict__ V,
                                           int idxa, int idxb, int tt, int lane,
                                           float vbuf[16])
{
    constexpr int KSH = (KP == 8) ? 3 : 2;
#pragma unroll
    for (int e = 0; e < 16; ++e) {
        const int p = e >> KSH;
        int k = e & (KP - 1);
        if (k >= KREAL) k = 0;
        const int li = (tt * PT + p) * 6 + k;
        const int j = (li < 64) ? __builtin_amdgcn_readlane(idxa, li)
                                : __builtin_amdgcn_readlane(idxb, li - 64);
        vbuf[e] = V[(size_t)j * 64 + lane];
    }
}

template <int PT>
__device__ __forceinline__ void load_urows(const float* __restrict__ U, int pb0,
                                           int tt, int lane, float ubuf[PT])
{
#pragma unroll
    for (int p = 0; p < PT; ++p)
        ubuf[p] = U[(size_t)(pb0 + tt * PT + p) * 64 + lane];
}

// stage relu(u+v) hi/lo bf16 rows into wave-private LDS, then 24 MFMA.
template <int KSH>
__device__ __forceinline__ void stage_mfma(char* base, int lane,
                                           const float vbuf[16], const float ubuf[],
                                           const v8s bh[4][2], const v8s bl[4][2],
                                           f32x4 acc[4])
{
#pragma unroll
    for (int e = 0; e < 16; ++e) {
        const int p = e >> KSH;
        float tv = ubuf[p] + vbuf[e];
        tv = fmaxf(tv, 0.0f);
        const unsigned int tu = __float_as_uint(tv);
        const unsigned int hi = tu & 0xffff0000u;
        const float lo = tv - __uint_as_float(hi);
        *((short*)(base + e * 272) + lane)       = (short)(hi >> 16);
        *((short*)(base + e * 272 + 128) + lane) = (short)(__float_as_uint(lo) >> 16);
    }
    __builtin_amdgcn_wave_barrier();
    __builtin_amdgcn_s_waitcnt(0xc07f);   // lgkmcnt(0): ds_writes visible

    v8s ah[2], al[2];
#pragma unroll
    for (int ks = 0; ks < 2; ++ks) {
        ah[ks] = *(const v8s*)(base + (lane & 15) * 272 + ks * 64 + (lane >> 4) * 16);
        al[ks] = *(const v8s*)(base + (lane & 15) * 272 + 128 + ks * 64 + (lane >> 4) * 16);
    }
#pragma unroll
    for (int nt = 0; nt < 4; ++nt) acc[nt] = (f32x4){0.f, 0.f, 0.f, 0.f};
#pragma unroll
    for (int nt = 0; nt < 4; ++nt) {
#pragma unroll
        for (int ks = 0; ks < 2; ++ks) {
            acc[nt] = __builtin_amdgcn_mfma_f32_16x16x32_bf16(ah[ks], bh[nt][ks], acc[nt], 0, 0, 0);
            acc[nt] = __builtin_amdgcn_mfma_f32_16x16x32_bf16(ah[ks], bl[nt][ks], acc[nt], 0, 0, 0);
            acc[nt] = __builtin_amdgcn_mfma_f32_16x16x32_bf16(al[ks], bh[nt][ks], acc[nt], 0, 0, 0);
        }
    }
}

// ---------------------------------------------------------------------------
// Kernel 1: top-6 kNN, v3.
//  - Q=4 queries/thread (keeps the 4x LDS-issue amortization that is valid)
//  - 16 chunks of 64 queries -> grid 1024 = 4 blocks/CU (occupancy back up)
//  - 16 candidate subs live in 16 lanes of one wave: per-sub top-4s merged
//    with an in-wave shfl_xor keep-6 butterfly (no sd/thr LDS, no barrier).
//    Threshold = 6th smallest of 64-value superset (tighter than old 32).
//  - ci/cn transposed to [qi][slot][thread] u16/u8: 2B lane stride, no bank
//    conflicts. LDS total 33KB -> 4 blocks/CU.
//  - refine pass identical fp32 math + index tie-break -> identical output.
// ---------------------------------------------------------------------------
__global__ __launch_bounds__(256) void knn6_kernel(const float* __restrict__ pos,
                                                   int* __restrict__ idx)
{
    __shared__ float4 pts[NP];                 // 16 KB
    __shared__ unsigned short ci[4][8][256];   // 16 KB  [qi][slot][thread]
    __shared__ unsigned char  cn[4][256];      // 1 KB   [qi][thread]

    const int blk = blockIdx.x;
    const int b = blk >> 4;
    const int chunk = blk & 15;                // 16 chunks of 64 queries
    const int t = threadIdx.x;
    const float* gp = pos + (size_t)b * NP * 3;
    for (int q = t; q < NP; q += 256) {
        float x = gp[q * 3 + 0], y = gp[q * 3 + 1], z = gp[q * 3 + 2];
        pts[q] = make_float4(x, y, z, x * x + y * y + z * z);
    }
    __syncthreads();

    const int qg = t >> 4;              // query group 0..15 (4 queries each)
    const int sub = t & 15;             // candidate sub-stream 0..15
    const int qb = chunk * 64 + qg * 4;

    float4 pi[4]; float sqi[4];
#pragma unroll
    for (int x = 0; x < 4; ++x) { pi[x] = pts[qb + x]; sqi[x] = pi[x].w; }

    // ---- pass 1: per-(query,sub) top-4 over 64 candidates -----------------
    float d0[4], d1[4], d2v[4], d3[4];
#pragma unroll
    for (int x = 0; x < 4; ++x) { d0[x] = 1e30f; d1[x] = 1e30f; d2v[x] = 1e30f; d3[x] = 1e30f; }

#pragma unroll 4
    for (int it = 0; it < 64; ++it) {
        const int q = (it << 4) | sub;
        const float4 pq = pts[q];
#pragma unroll
        for (int x = 0; x < 4; ++x) {
            const float dq = dist2(pi[x], sqi[x], pq);
            d3[x]  = __builtin_amdgcn_fmed3f(dq, d2v[x], d3[x]);
            d2v[x] = __builtin_amdgcn_fmed3f(dq, d1[x], d2v[x]);
            d1[x]  = __builtin_amdgcn_fmed3f(dq, d0[x], d1[x]);
            d0[x]  = fminf(dq, d0[x]);
        }
    }

    // ---- in-wave butterfly merge: thr = 6th smallest of 16 subs x top-4 ---
    float th[4];
#pragma unroll
    for (int x = 0; x < 4; ++x) {
        float e0 = d0[x], e1 = d1[x], e2 = d2v[x], e3 = d3[x], e4 = 1e30f, e5 = 1e30f;
#pragma unroll
        for (int st = 1; st <= 8; st <<= 1) {
            const float f0 = __shfl_xor(e0, st);
            const float f1 = __shfl_xor(e1, st);
            const float f2 = __shfl_xor(e2, st);
            const float f3 = __shfl_xor(e3, st);
            const float f4 = __shfl_xor(e4, st);
            const float f5 = __shfl_xor(e5, st);
#pragma unroll
            for (int k = 0; k < 6; ++k) {
                const float f = (k == 0) ? f0 : (k == 1) ? f1 : (k == 2) ? f2
                              : (k == 3) ? f3 : (k == 4) ? f4 : f5;
                e5 = __builtin_amdgcn_fmed3f(f, e4, e5);
                e4 = __builtin_amdgcn_fmed3f(f, e3, e4);
                e3 = __builtin_amdgcn_fmed3f(f, e2, e3);
                e2 = __builtin_amdgcn_fmed3f(f, e1, e2);
                e1 = __builtin_amdgcn_fmed3f(f, e0, e1);
                e0 = fminf(f, e0);
            }
        }
        th[x] = e5;
    }

    // ---- pass 2: collect candidates <= thr (ring cap 8 per (query,sub)) ---
    int cnt0 = 0, cnt1 = 0, cnt2 = 0, cnt3 = 0;
#pragma unroll 4
    for (int it = 0; it < 64; ++it) {
        const int q = (it << 4) | sub;
        const float4 pq = pts[q];
        {
            const float dq = dist2(pi[0], sqi[0], pq);
            if (dq <= th[0]) { ci[0][cnt0 & 7][t] = (unsigned short)q; ++cnt0; }
        }
        {
            const float dq = dist2(pi[1], sqi[1], pq);
            if (dq <= th[1]) { ci[1][cnt1 & 7][t] = (unsigned short)q; ++cnt1; }
        }
        {
            const float dq = dist2(pi[2], sqi[2], pq);
            if (dq <= th[2]) { ci[2][cnt2 & 7][t] = (unsigned short)q; ++cnt2; }
        }
        {
            const float dq = dist2(pi[3], sqi[3], pq);
            if (dq <= th[3]) { ci[3][cnt3 & 7][t] = (unsigned short)q; ++cnt3; }
        }
    }
    cn[0][t] = (unsigned char)((cnt0 > 8) ? 8 : cnt0);
    cn[1][t] = (unsigned char)((cnt1 > 8) ? 8 : cnt1);
    cn[2][t] = (unsigned char)((cnt2 > 8) ? 8 : cnt2);
    cn[3][t] = (unsigned char)((cnt3 > 8) ? 8 : cnt3);
    __syncthreads();

    // ---- refine: exact top-6 with index tie-break (identical network) -----
    if (t < 64) {
        const int il = chunk * 64 + t;
        const float4 pit = pts[il];
        const float sqit = pit.w;
        const int qgq = t >> 2;             // query group of this query
        const int qi = t & 3;
        float e0 = 1e30f, e1 = 1e30f, e2 = 1e30f, e3 = 1e30f, e4 = 1e30f, e5 = 1e30f;
        int j0 = 0x7fffffff, j1 = 0x7fffffff, j2 = 0x7fffffff,
            j3 = 0x7fffffff, j4 = 0x7fffffff, j5 = 0x7fffffff;
#pragma unroll
        for (int s = 0; s < 16; ++s) {
            const int tid = qgq * 16 + s;
            const int n = cn[qi][tid];
            for (int e = 0; e < n; ++e) {
                const int q = ci[qi][e][tid];
                const float d = dist2(pit, sqit, pts[q]);
                if (d < e5 || (d == e5 && q < j5)) {
                    if (d < e4 || (d == e4 && q < j4)) {
                        e5 = e4; j5 = j4;
                        if (d < e3 || (d == e3 && q < j3)) {
                            e4 = e3; j4 = j3;
                            if (d < e2 || (d == e2 && q < j2)) {
                                e3 = e2; j3 = j2;
                                if (d < e1 || (d == e1 && q < j1)) {
                                    e2 = e1; j2 = j1;
                                    if (d < e0 || (d == e0 && q < j0)) {
                                        e1 = e0; j1 = j0; e0 = d; j0 = q;
                                    } else { e1 = d; j1 = q; }
                                } else { e2 = d; j2 = q; }
                            } else { e3 = d; j3 = q; }
                        } else { e4 = d; j4 = q; }
                    } else { e5 = d; j5 = q; }
                }
            }
        }
        const int gb = b * NP;
        int* op = idx + (size_t)(gb + il) * 6;
        op[0] = gb + j0; op[1] = gb + j1; op[2] = gb + j2;
        op[3] = gb + j3; op[4] = gb + j4; op[5] = gb + j5;
    }
}

// ---------------------------------------------------------------------------
// Kernel 2: layer-1 prep: U1 = b1 + pos@(W1a-W1c); Vpos = pos@(W1b+W1c).
// ---------------------------------------------------------------------------
__global__ __launch_bounds__(256) void prep1_kernel(
    const float* __restrict__ pos, const float* __restrict__ W1,
    const float* __restrict__ b1, float* __restrict__ Uout,
    float* __restrict__ Vout)
{
    const int gid = blockIdx.x * 256 + threadIdx.x;
    const int i = gid >> 6;
    const int c = gid & 63;
    const float px = pos[i * 3 + 0], py = pos[i * 3 + 1], pz = pos[i * 3 + 2];
    float u = b1[c];
    u = fmaf(px, W1[0 * 64 + c] - W1[6 * 64 + c], u);
    u = fmaf(py, W1[1 * 64 + c] - W1[7 * 64 + c], u);
    u = fmaf(pz, W1[2 * 64 + c] - W1[8 * 64 + c], u);
    Uout[(size_t)i * 64 + c] = u;
    float v =      px * (W1[3 * 64 + c] + W1[6 * 64 + c]);
    v = fmaf(py, W1[4 * 64 + c] + W1[7 * 64 + c], v);
    v = fmaf(pz, W1[5 * 64 + c] + W1[8 * 64 + c], v);
    Vout[(size_t)i * 64 + c] = v;
}

// ---------------------------------------------------------------------------
// Kernel 3: FUSED edge(N) + uv(N+1), software-pipelined staging.
// ---------------------------------------------------------------------------
template <int PT, int KP, int KREAL>
__global__ __launch_bounds__(256) void fused_edge_uv_kernel(
    const float* __restrict__ U, const float* __restrict__ V,
    const int* __restrict__ idx,
    const float* __restrict__ W2, const float* __restrict__ b2,
    const float* __restrict__ W1n, const float* __restrict__ b1n,
    const float* __restrict__ pos,
    float* __restrict__ Uout, float* __restrict__ Vout,
    float* __restrict__ pooled_zero)
{
    __shared__ char  stag[4 * 16 * 272];
    __shared__ float hlds[4][16 * 68];
    const int t = threadIdx.x;
    const int lane = t & 63;
    const int wv = __builtin_amdgcn_readfirstlane(t >> 6);
    char* base = &stag[wv * 16 * 272];
    float* hw = &hlds[wv][0];
    const int col = lane & 15;
    const int quad = lane >> 4;
    constexpr int KSH = (KP == 8) ? 3 : 2;
    constexpr int TPW = 16 / PT;

    if (pooled_zero != nullptr && blockIdx.x == 0) {
#pragma unroll
        for (int i = 0; i < 16; ++i) pooled_zero[i * 256 + t] = 0.0f;
    }

    const int x = blockIdx.x & 7;        // XCD slot
    const int r = blockIdx.x >> 3;       // 0..127
    const int g = x * 8 + (r & 7);       // graph
    const int sb = r >> 3;               // 0..15
    const int base16 = g * NP + sb * 64 + wv * 16;   // this wave's 16 points

    // preload ALL 96 neighbor indices for this wave (one coalesced load pair)
    const int idxa = idx[(size_t)base16 * 6 + lane];
    const int idxb = idx[(size_t)base16 * 6 + 64 + (lane & 31)];

    // ---- W2 B-frags (edge phase) ------------------------------------------
    v8s bh[4][2], bl[4][2];
#pragma unroll
    for (int nt = 0; nt < 4; ++nt) {
#pragma unroll
        for (int ks = 0; ks < 2; ++ks) {
            float w[8];
#pragma unroll
            for (int j = 0; j < 8; ++j)
                w[j] = W2[(size_t)(ks * 32 + quad * 8 + j) * 64 + nt * 16 + col];
            pack8(w, bh[nt][ks], bl[nt][ks]);
        }
    }
    float b2v[4];
#pragma unroll
    for (int nt = 0; nt < 4; ++nt) b2v[nt] = b2[nt * 16 + col];

    // ---- edge phase: double-buffered row prefetch across tiles ------------
    {
        float va[16], vb[16], ua[PT], ub[PT];
        load_vrows<PT, KP, KREAL>(V, idxa, idxb, 0, lane, va);
        load_urows<PT>(U, base16, 0, lane, ua);

#pragma unroll
        for (int t2 = 0; t2 < TPW; t2 += 2) {
            if (t2 + 1 < TPW) {
                load_vrows<PT, KP, KREAL>(V, idxa, idxb, t2 + 1, lane, vb);
                load_urows<PT>(U, base16, t2 + 1, lane, ub);
            }
            {
                f32x4 acc[4];
                stage_mfma<KSH>(base, lane, va, ua, bh, bl, acc);
#pragma unroll
                for (int nt = 0; nt < 4; ++nt) {
                    float m = fmaxf(fmaxf(acc[nt].x, acc[nt].y), fmaxf(acc[nt].z, acc[nt].w));
                    if (KP == 4) {
                        const float z = fmaxf(m + b2v[nt], 0.0f);
                        hw[(t2 * 4 + quad) * 68 + nt * 16 + col] = z;
                    } else {
                        m = fmaxf(m, __shfl_xor(m, 16));
                        const float z = fmaxf(m + b2v[nt], 0.0f);
                        if ((lane & 16) == 0)
                            hw[(t2 * 2 + (lane >> 5)) * 68 + nt * 16 + col] = z;
                    }
                }
            }
            if (t2 + 1 < TPW) {
                if (t2 + 2 < TPW) {
                    load_vrows<PT, KP, KREAL>(V, idxa, idxb, t2 + 2, lane, va);
                    load_urows<PT>(U, base16, t2 + 2, lane, ua);
                }
                f32x4 acc[4];
                stage_mfma<KSH>(base, lane, vb, ub, bh, bl, acc);
#pragma unroll
                for (int nt = 0; nt < 4; ++nt) {
                    float m = fmaxf(fmaxf(acc[nt].x, acc[nt].y), fmaxf(acc[nt].z, acc[nt].w));
                    if (KP == 4) {
                        const float z = fmaxf(m + b2v[nt], 0.0f);
                        hw[((t2 + 1) * 4 + quad) * 68 + nt * 16 + col] = z;
                    } else {
                        m = fmaxf(m, __shfl_xor(m, 16));
                        const float z = fmaxf(m + b2v[nt], 0.0f);
                        if ((lane & 16) == 0)
                            hw[((t2 + 1) * 2 + (lane >> 5)) * 68 + nt * 16 + col] = z;
                    }
                }
            }
        }
    }
    __builtin_amdgcn_wave_barrier();
    __builtin_amdgcn_s_waitcnt(0xc07f);   // h rows visible to this wave

    // ---- uv phase: [U'|V'] = h @ [W1n_a|W1n_b] ----------------------------
    v8s ah[2], al[2];
#pragma unroll
    for (int ks = 0; ks < 2; ++ks) {
        float w[8];
        const float4 f0 = *(const float4*)(hw + col * 68 + ks * 32 + quad * 8);
        const float4 f1 = *(const float4*)(hw + col * 68 + ks * 32 + quad * 8 + 4);
        w[0] = f0.x; w[1] = f0.y; w[2] = f0.z; w[3] = f0.w;
        w[4] = f1.x; w[5] = f1.y; w[6] = f1.z; w[7] = f1.w;
        pack8(w, ah[ks], al[ks]);
    }

    float prx[4], pry[4], prz[4];
#pragma unroll
    for (int r2 = 0; r2 < 4; ++r2) {
        const int pt = base16 + quad * 4 + r2;
        prx[r2] = pos[pt * 3 + 0];
        pry[r2] = pos[pt * 3 + 1];
        prz[r2] = pos[pt * 3 + 2];
    }
    float wcx[4], wcy[4], wcz[4], b1v[4];
#pragma unroll
    for (int nt = 0; nt < 4; ++nt) {
        wcx[nt] = W1n[128 * 64 + nt * 16 + col];
        wcy[nt] = W1n[129 * 64 + nt * 16 + col];
        wcz[nt] = W1n[130 * 64 + nt * 16 + col];
        b1v[nt] = b1n[nt * 16 + col];
    }

    for (int half = 1; half >= 0; --half) {
        v8s bh2[4][2], bl2[4][2];
#pragma unroll
        for (int nt = 0; nt < 4; ++nt) {
#pragma unroll
            for (int ks = 0; ks < 2; ++ks) {
                float w[8];
#pragma unroll
                for (int j = 0; j < 8; ++j)
                    w[j] = W1n[(size_t)(half * 64 + ks * 32 + quad * 8 + j) * 64 + nt * 16 + col];
                pack8(w, bh2[nt][ks], bl2[nt][ks]);
            }
        }

        f32x4 acc[4];
#pragma unroll
        for (int nt = 0; nt < 4; ++nt) acc[nt] = (f32x4){0.f, 0.f, 0.f, 0.f};
#pragma unroll
        for (int nt = 0; nt < 4; ++nt) {
#pragma unroll
            for (int ks = 0; ks < 2; ++ks) {
                acc[nt] = __builtin_amdgcn_mfma_f32_16x16x32_bf16(ah[ks], bh2[nt][ks], acc[nt], 0, 0, 0);
                acc[nt] = __builtin_amdgcn_mfma_f32_16x16x32_bf16(ah[ks], bl2[nt][ks], acc[nt], 0, 0, 0);
                acc[nt] = __builtin_amdgcn_mfma_f32_16x16x32_bf16(al[ks], bh2[nt][ks], acc[nt], 0, 0, 0);
            }
        }

        float* outp = half ? Vout : Uout;
#pragma unroll
        for (int nt = 0; nt < 4; ++nt) {
            const float* a = (const float*)&acc[nt];
#pragma unroll
            for (int r2 = 0; r2 < 4; ++r2) {
                float dotp = fmaf(prz[r2], wcz[nt], fmaf(pry[r2], wcy[nt], prx[r2] * wcx[nt]));
                float val = half ? (a[r2] + dotp) : (a[r2] + b1v[nt] - dotp);
                outp[(size_t)(base16 + quad * 4 + r2) * 64 + nt * 16 + col] = val;
            }
        }
    }
}

// ---------------------------------------------------------------------------
// Kernel 4: final edge layer, pipelined staging; pool-max in registers.
// ---------------------------------------------------------------------------
template <int PT, int KP, int KREAL, int TPW>
__global__ __launch_bounds__(256) void edge3_mfma_kernel(
    const float* __restrict__ U, const float* __restrict__ V,
    const int* __restrict__ idx,
    const float* __restrict__ W2, const float* __restrict__ b2,
    float* __restrict__ outp)
{
    __shared__ char ldsbuf[4 * 16 * 272];
    const int t = threadIdx.x;
    const int lane = t & 63;
    const int wv = __builtin_amdgcn_readfirstlane(t >> 6);
    char* base = &ldsbuf[wv * 16 * 272];
    const int col = lane & 15;
    const int quad = lane >> 4;
    constexpr int KSH = (KP == 8) ? 3 : 2;

    const int x = blockIdx.x & 7;
    const int r = blockIdx.x >> 3;
    const int g = x * 8 + (r & 7);
    const int sb = r >> 3;
    const int pbase = g * NP + (sb * 4 + wv) * (PT * TPW);   // 8 consecutive points

    const int idxa = idx[(size_t)pbase * 6 + lane];

    v8s bh[4][2], bl[4][2];
#pragma unroll
    for (int nt = 0; nt < 4; ++nt) {
#pragma unroll
        for (int ks = 0; ks < 2; ++ks) {
            float w[8];
#pragma unroll
            for (int j = 0; j < 8; ++j)
                w[j] = W2[(size_t)(ks * 32 + quad * 8 + j) * 64 + nt * 16 + col];
            pack8(w, bh[nt][ks], bl[nt][ks]);
        }
    }
    float b2v[4];
#pragma unroll
    for (int nt = 0; nt < 4; ++nt) b2v[nt] = b2[nt * 16 + col];

    float va[16], vb[16], ua[PT], ub[PT];
    load_vrows<PT, KP, KREAL>(V, idxa, idxa, 0, lane, va);
    load_urows<PT>(U, pbase, 0, lane, ua);

    float zacc[4] = {0.f, 0.f, 0.f, 0.f};

#pragma unroll
    for (int t2 = 0; t2 < TPW; t2 += 2) {
        if (t2 + 1 < TPW) {
            load_vrows<PT, KP, KREAL>(V, idxa, idxa, t2 + 1, lane, vb);
            load_urows<PT>(U, pbase, t2 + 1, lane, ub);
        }
        {
            f32x4 acc[4];
            stage_mfma<KSH>(base, lane, va, ua, bh, bl, acc);
#pragma unroll
            for (int nt = 0; nt < 4; ++nt) {
                float m = fmaxf(fmaxf(acc[nt].x, acc[nt].y), fmaxf(acc[nt].z, acc[nt].w));
                zacc[nt] = fmaxf(zacc[nt], fmaxf(m + b2v[nt], 0.0f));
            }
        }
        if (t2 + 1 < TPW) {
            if (t2 + 2 < TPW) {
                load_vrows<PT, KP, KREAL>(V, idxa, idxa, t2 + 2, lane, va);
                load_urows<PT>(U, pbase, t2 + 2, lane, ua);
            }
            f32x4 acc[4];
            stage_mfma<KSH>(base, lane, vb, ub, bh, bl, acc);
#pragma unroll
            for (int nt = 0; nt < 4; ++nt) {
                float m = fmaxf(fmaxf(acc[nt].x, acc[nt].y), fmaxf(acc[nt].z, acc[nt].w));
                zacc[nt] = fmaxf(zacc[nt], fmaxf(m + b2v[nt], 0.0f));
            }
        }
    }

#pragma unroll
    for (int nt = 0; nt < 4; ++nt) {
        float zm = fmaxf(zacc[nt], __shfl_xor(zacc[nt], 16));
        zm = fmaxf(zm, __shfl_xor(zm, 32));
        if (quad == 0) {
            atomicMax((unsigned int*)(outp + (size_t)g * 64 + nt * 16 + col),
                      __float_as_uint(zm));
        }
    }
}

// ---------------------------------------------------------------------------
// Kernel 5: final 64->6 regression from pooled. 6 blocks x 64 threads.
// ---------------------------------------------------------------------------
__global__ __launch_bounds__(64) void reg_kernel(
    const float* __restrict__ pooled, const float* __restrict__ regW,
    const float* __restrict__ regb, float* __restrict__ out)
{
    const int t = blockIdx.x * 64 + threadIdx.x;
    const int b = t / 6;
    const int o = t - b * 6;
    if (t < NB * 6) {
        float z = regb[o];
        const float* pb = pooled + (size_t)b * 64;
        for (int c = 0; c < 64; ++c) z = fmaf(pb[c], regW[c * 6 + o], z);
        out[b * 6 + o] = z;
    }
}

// ---------------------------------------------------------------------------
extern "C" void kernel_launch(void* const* d_in, const int* in_sizes, int n_in,
                              void* d_out, int out_size, void* d_ws, size_t ws_size,
                              hipStream_t stream)
{
    (void)in_sizes; (void)n_in; (void)out_size; (void)ws_size;
    const float* pos   = (const float*)d_in[1];
    const float* c1W1  = (const float*)d_in[3];
    const float* c1b1  = (const float*)d_in[4];
    const float* c1W2  = (const float*)d_in[5];
    const float* c1b2  = (const float*)d_in[6];
    const float* c2W1  = (const float*)d_in[7];
    const float* c2b1  = (const float*)d_in[8];
    const float* c2W2  = (const float*)d_in[9];
    const float* c2b2  = (const float*)d_in[10];
    const float* c3W1  = (const float*)d_in[11];
    const float* c3b1  = (const float*)d_in[12];
    const float* c3W2  = (const float*)d_in[13];
    const float* c3b2  = (const float*)d_in[14];
    const float* regW  = (const float*)d_in[15];
    const float* regb  = (const float*)d_in[16];
    float* out = (float*)d_out;

    // workspace: idx | A | C | D | E | pooled  (A,C,D,E are 65536x64 fp32)
    char* ws = (char*)d_ws;
    int*   idx = (int*)ws;                                    // 1.5 MB
    float* A = (float*)(ws + 1572864);
    float* C = (float*)(ws + 1572864 + 1 * 16777216);
    float* D = (float*)(ws + 1572864 + 2 * 16777216);
    float* E = (float*)(ws + 1572864 + 3 * 16777216);
    float* pooled = (float*)(ws + 1572864 + 4 * 16777216);    // 16 KB

    // prep: U1 -> D, Vpos -> C ; kNN single launch
    prep1_kernel<<<NPTS * 64 / 256, 256, 0, stream>>>(pos, c1W1, c1b1, D, C);
    knn6_kernel<<<NB * 16, 256, 0, stream>>>(pos, idx);

    // fused layer1-edge + layer2-uv: reads (D=U1, C=Vpos) -> U2->A, V2->E
    fused_edge_uv_kernel<2, 8, 6><<<1024, 256, 0, stream>>>(
        D, C, idx, c1W2, c1b2, c2W1, c2b1, pos, A, E, nullptr);

    // fused layer2-edge + layer3-uv: reads (A=U2, E=V2) -> U3->D, V3->C
    // (block 0 zeroes pooled)
    fused_edge_uv_kernel<4, 4, 4><<<1024, 256, 0, stream>>>(
        A, E, idx, c2W2, c2b2, c3W1, c3b1, pos, D, C, pooled);

    // layer3 edge -> atomic max into pooled
    edge3_mfma_kernel<4, 4, 3, 2><<<2048, 256, 0, stream>>>(
        D, C, idx, c3W2, c3b2, pooled);

    // final regression
    reg_kernel<<<6, 64, 0, stream>>>(pooled, regW, regb, out);
}

// Round 5
// 215.302 us; speedup vs baseline: 1.0802x; 1.0802x over previous
//
#include <hip/hip_runtime.h>
#include <cstddef>

#define NB 64
#define NP 1024
#define NPTS (NB * NP)

typedef __attribute__((ext_vector_type(8))) short v8s;
typedef __attribute__((ext_vector_type(4))) float f32x4;

__device__ __forceinline__ float dist2(const float4 pi, const float sqi, const float4 pq) {
    const float dot = fmaf(pi.z, pq.z, fmaf(pi.y, pq.y, pi.x * pq.x));
    return fmaf(-2.0f, dot, sqi + pq.w);
}

__device__ __forceinline__ void pack8(const float* w, v8s& hv, v8s& lv) {
    union { v8s v; unsigned int u[4]; } H, L;
#pragma unroll
    for (int p = 0; p < 4; ++p) {
        unsigned int a = __float_as_uint(w[2 * p]);
        unsigned int b = __float_as_uint(w[2 * p + 1]);
        unsigned int ha = a & 0xffff0000u, hb = b & 0xffff0000u;
        H.u[p] = (ha >> 16) | hb;
        float la = w[2 * p] - __uint_as_float(ha);
        float lb = w[2 * p + 1] - __uint_as_float(hb);
        L.u[p] = (__float_as_uint(la) >> 16) | (__float_as_uint(lb) & 0xffff0000u);
    }
    hv = H.v; lv = L.v;
}

// ---- shared helpers for the edge kernels ----------------------------------

// prefetch the 16 V-rows of one tile into registers. Duplicate-k slots
// (k >= KREAL) reuse the k=0 row already loaded (identical value, no gather).
template <int PT, int KP, int KREAL>
__device__ __forceinline__ void load_vrows(const float* __restrict__ V,
                                           int idxa, int idxb, int tt, int lane,
                                           float vbuf[16])
{
    constexpr int KSH = (KP == 8) ? 3 : 2;
#pragma unroll
    for (int e = 0; e < 16; ++e) {
        const int p = e >> KSH;
        const int k = e & (KP - 1);
        if (k >= KREAL) continue;       // filled below from the k=0 slot
        const int li = (tt * PT + p) * 6 + k;
        const int j = (li < 64) ? __builtin_amdgcn_readlane(idxa, li)
                                : __builtin_amdgcn_readlane(idxb, li - 64);
        vbuf[e] = V[(size_t)j * 64 + lane];
    }
#pragma unroll
    for (int e = 0; e < 16; ++e) {
        const int p = e >> KSH;
        const int k = e & (KP - 1);
        if (k >= KREAL) vbuf[e] = vbuf[p << KSH];
    }
}

template <int PT>
__device__ __forceinline__ void load_urows(const float* __restrict__ U, int pb0,
                                           int tt, int lane, float ubuf[PT])
{
#pragma unroll
    for (int p = 0; p < PT; ++p)
        ubuf[p] = U[(size_t)(pb0 + tt * PT + p) * 64 + lane];
}

// stage relu(u+v) hi/lo bf16 rows into wave-private LDS, then 24 MFMA.
template <int KSH>
__device__ __forceinline__ void stage_mfma(char* base, int lane,
                                           const float vbuf[16], const float ubuf[],
                                           const v8s bh[4][2], const v8s bl[4][2],
                                           f32x4 acc[4])
{
#pragma unroll
    for (int e = 0; e < 16; ++e) {
        const int p = e >> KSH;
        float tv = ubuf[p] + vbuf[e];
        tv = fmaxf(tv, 0.0f);
        const unsigned int tu = __float_as_uint(tv);
        const unsigned int hi = tu & 0xffff0000u;
        const float lo = tv - __uint_as_float(hi);
        *((short*)(base + e * 272) + lane)       = (short)(hi >> 16);
        *((short*)(base + e * 272 + 128) + lane) = (short)(__float_as_uint(lo) >> 16);
    }
    __builtin_amdgcn_wave_barrier();
    __builtin_amdgcn_s_waitcnt(0xc07f);   // lgkmcnt(0): ds_writes visible

    v8s ah[2], al[2];
#pragma unroll
    for (int ks = 0; ks < 2; ++ks) {
        ah[ks] = *(const v8s*)(base + (lane & 15) * 272 + ks * 64 + (lane >> 4) * 16);
        al[ks] = *(const v8s*)(base + (lane & 15) * 272 + 128 + ks * 64 + (lane >> 4) * 16);
    }
#pragma unroll
    for (int nt = 0; nt < 4; ++nt) acc[nt] = (f32x4){0.f, 0.f, 0.f, 0.f};
#pragma unroll
    for (int nt = 0; nt < 4; ++nt) {
#pragma unroll
        for (int ks = 0; ks < 2; ++ks) {
            acc[nt] = __builtin_amdgcn_mfma_f32_16x16x32_bf16(ah[ks], bh[nt][ks], acc[nt], 0, 0, 0);
            acc[nt] = __builtin_amdgcn_mfma_f32_16x16x32_bf16(ah[ks], bl[nt][ks], acc[nt], 0, 0, 0);
            acc[nt] = __builtin_amdgcn_mfma_f32_16x16x32_bf16(al[ks], bh[nt][ks], acc[nt], 0, 0, 0);
        }
    }
}

// ---------------------------------------------------------------------------
// Kernel 1: top-6 kNN (proven two-pass form) + fused layer-1 prep tail:
//   U1 = b1 + pos@(W1a-W1c) -> D ; Vpos = pos@(W1b+W1c) -> C.
// The prep tail runs on all 256 threads after the last barrier while wave 0
// finishes the top-6 refine (no barrier between them; independent outputs).
// Identical fp32 sequences to the old prep1_kernel -> bit-identical results.
// ---------------------------------------------------------------------------
__global__ __launch_bounds__(256) void knn6_prep_kernel(
    const float* __restrict__ pos,
    const float* __restrict__ W1, const float* __restrict__ b1,
    int* __restrict__ idx,
    float* __restrict__ Uout, float* __restrict__ Vout)
{
    __shared__ float4 pts[NP];
    __shared__ float  sd[256 * 4];
    __shared__ float  thr[64];
    __shared__ int    ci[256 * 8];
    __shared__ int    cn[256];

    const int blk = blockIdx.x;
    const int b = blk >> 4;
    const int chunk = blk & 15;
    const int t = threadIdx.x;
    const float* gp = pos + (size_t)b * NP * 3;
    for (int q = t; q < NP; q += 256) {
        float x = gp[q * 3 + 0], y = gp[q * 3 + 1], z = gp[q * 3 + 2];
        pts[q] = make_float4(x, y, z, x * x + y * y + z * z);
    }
    __syncthreads();

    const int p = t >> 2;
    const int sub = t & 3;
    const int il = chunk * 64 + p;
    const float4 pi = pts[il];
    const float sqi = pi.w;

    float d0 = 1e30f, d1 = 1e30f, d2v = 1e30f, d3 = 1e30f;
#pragma unroll 4
    for (int it = 0; it < 256; ++it) {
        const int q = (it << 2) | sub;
        const float dq = dist2(pi, sqi, pts[q]);
        d3  = __builtin_amdgcn_fmed3f(dq, d2v, d3);
        d2v = __builtin_amdgcn_fmed3f(dq, d1, d2v);
        d1  = __builtin_amdgcn_fmed3f(dq, d0, d1);
        d0  = fminf(dq, d0);
    }
    {
        float* sp = &sd[t * 4];
        sp[0] = d0; sp[1] = d1; sp[2] = d2v; sp[3] = d3;
    }
    __syncthreads();

    if (t < 64) {
        float e0 = 1e30f, e1 = 1e30f, e2 = 1e30f, e3 = 1e30f, e4 = 1e30f, e5 = 1e30f;
#pragma unroll
        for (int s = 0; s < 4; ++s) {
            const float* q4 = &sd[(t * 4 + s) * 4];
#pragma unroll
            for (int k = 0; k < 4; ++k) {
                const float d = q4[k];
                e5 = __builtin_amdgcn_fmed3f(d, e4, e5);
                e4 = __builtin_amdgcn_fmed3f(d, e3, e4);
                e3 = __builtin_amdgcn_fmed3f(d, e2, e3);
                e2 = __builtin_amdgcn_fmed3f(d, e1, e2);
                e1 = __builtin_amdgcn_fmed3f(d, e0, e1);
                e0 = fminf(d, e0);
            }
        }
        thr[t] = e5;
    }
    __syncthreads();

    const float th = thr[p];
    int cnt = 0;
#pragma unroll 4
    for (int it = 0; it < 256; ++it) {
        const int q = (it << 2) | sub;
        const float dq = dist2(pi, sqi, pts[q]);
        if (dq <= th) {
            ci[t * 8 + (cnt & 7)] = q;
            ++cnt;
        }
    }
    cn[t] = (cnt > 8) ? 8 : cnt;
    __syncthreads();

    if (t < 64) {
        const float4 pit = pts[chunk * 64 + t];
        const float sqit = pit.w;
        float e0 = 1e30f, e1 = 1e30f, e2 = 1e30f, e3 = 1e30f, e4 = 1e30f, e5 = 1e30f;
        int j0 = 0x7fffffff, j1 = 0x7fffffff, j2 = 0x7fffffff,
            j3 = 0x7fffffff, j4 = 0x7fffffff, j5 = 0x7fffffff;
#pragma unroll
        for (int s = 0; s < 4; ++s) {
            const int tid = t * 4 + s;
            const int n = cn[tid];
            for (int e = 0; e < n; ++e) {
                const int q = ci[tid * 8 + e];
                const float d = dist2(pit, sqit, pts[q]);
                if (d < e5 || (d == e5 && q < j5)) {
                    if (d < e4 || (d == e4 && q < j4)) {
                        e5 = e4; j5 = j4;
                        if (d < e3 || (d == e3 && q < j3)) {
                            e4 = e3; j4 = j3;
                            if (d < e2 || (d == e2 && q < j2)) {
                                e3 = e2; j3 = j2;
                                if (d < e1 || (d == e1 && q < j1)) {
                                    e2 = e1; j2 = j1;
                                    if (d < e0 || (d == e0 && q < j0)) {
                                        e1 = e0; j1 = j0; e0 = d; j0 = q;
                                    } else { e1 = d; j1 = q; }
                                } else { e2 = d; j2 = q; }
                            } else { e3 = d; j3 = q; }
                        } else { e4 = d; j4 = q; }
                    } else { e5 = d; j5 = q; }
                }
            }
        }
        const int gb = b * NP;
        int* op = idx + (size_t)(gb + chunk * 64 + t) * 6;
        op[0] = gb + j0; op[1] = gb + j1; op[2] = gb + j2;
        op[3] = gb + j3; op[4] = gb + j4; op[5] = gb + j5;
    }

    // ---- fused prep tail: 64 points x 64 channels (16 per thread) ---------
    {
        const int p2 = t >> 2;
        const int cb = (t & 3) * 16;
        const int il2 = chunk * 64 + p2;
        const float4 pp = pts[il2];
        const size_t gi = (size_t)(b * NP + il2) * 64;
#pragma unroll
        for (int cc = 0; cc < 16; ++cc) {
            const int c = cb + cc;
            float u = b1[c];
            u = fmaf(pp.x, W1[0 * 64 + c] - W1[6 * 64 + c], u);
            u = fmaf(pp.y, W1[1 * 64 + c] - W1[7 * 64 + c], u);
            u = fmaf(pp.z, W1[2 * 64 + c] - W1[8 * 64 + c], u);
            Uout[gi + c] = u;
            float v =      pp.x * (W1[3 * 64 + c] + W1[6 * 64 + c]);
            v = fmaf(pp.y, W1[4 * 64 + c] + W1[7 * 64 + c], v);
            v = fmaf(pp.z, W1[5 * 64 + c] + W1[8 * 64 + c], v);
            Vout[gi + c] = v;
        }
    }
}

// ---------------------------------------------------------------------------
// Kernel 2: FUSED edge(N) + uv(N+1), software-pipelined staging (round-1
// verified form).
// ---------------------------------------------------------------------------
template <int PT, int KP, int KREAL>
__global__ __launch_bounds__(256) void fused_edge_uv_kernel(
    const float* __restrict__ U, const float* __restrict__ V,
    const int* __restrict__ idx,
    const float* __restrict__ W2, const float* __restrict__ b2,
    const float* __restrict__ W1n, const float* __restrict__ b1n,
    const float* __restrict__ pos,
    float* __restrict__ Uout, float* __restrict__ Vout,
    float* __restrict__ pooled_zero)
{
    __shared__ char  stag[4 * 16 * 272];
    __shared__ float hlds[4][16 * 68];
    const int t = threadIdx.x;
    const int lane = t & 63;
    const int wv = __builtin_amdgcn_readfirstlane(t >> 6);
    char* base = &stag[wv * 16 * 272];
    float* hw = &hlds[wv][0];
    const int col = lane & 15;
    const int quad = lane >> 4;
    constexpr int KSH = (KP == 8) ? 3 : 2;
    constexpr int TPW = 16 / PT;

    if (pooled_zero != nullptr && blockIdx.x == 0) {
#pragma unroll
        for (int i = 0; i < 16; ++i) pooled_zero[i * 256 + t] = 0.0f;
    }

    const int x = blockIdx.x & 7;        // XCD slot
    const int r = blockIdx.x >> 3;       // 0..127
    const int g = x * 8 + (r & 7);       // graph
    const int sb = r >> 3;               // 0..15
    const int base16 = g * NP + sb * 64 + wv * 16;   // this wave's 16 points

    // preload ALL 96 neighbor indices for this wave (one coalesced load pair)
    const int idxa = idx[(size_t)base16 * 6 + lane];
    const int idxb = idx[(size_t)base16 * 6 + 64 + (lane & 31)];

    // ---- W2 B-frags (edge phase) ------------------------------------------
    v8s bh[4][2], bl[4][2];
#pragma unroll
    for (int nt = 0; nt < 4; ++nt) {
#pragma unroll
        for (int ks = 0; ks < 2; ++ks) {
            float w[8];
#pragma unroll
            for (int j = 0; j < 8; ++j)
                w[j] = W2[(size_t)(ks * 32 + quad * 8 + j) * 64 + nt * 16 + col];
            pack8(w, bh[nt][ks], bl[nt][ks]);
        }
    }
    float b2v[4];
#pragma unroll
    for (int nt = 0; nt < 4; ++nt) b2v[nt] = b2[nt * 16 + col];

    // ---- edge phase: double-buffered row prefetch across tiles ------------
    {
        float va[16], vb[16], ua[PT], ub[PT];
        load_vrows<PT, KP, KREAL>(V, idxa, idxb, 0, lane, va);
        load_urows<PT>(U, base16, 0, lane, ua);

#pragma unroll
        for (int t2 = 0; t2 < TPW; t2 += 2) {
            if (t2 + 1 < TPW) {
                load_vrows<PT, KP, KREAL>(V, idxa, idxb, t2 + 1, lane, vb);
                load_urows<PT>(U, base16, t2 + 1, lane, ub);
            }
            {
                f32x4 acc[4];
                stage_mfma<KSH>(base, lane, va, ua, bh, bl, acc);
#pragma unroll
                for (int nt = 0; nt < 4; ++nt) {
                    float m = fmaxf(fmaxf(acc[nt].x, acc[nt].y), fmaxf(acc[nt].z, acc[nt].w));
                    if (KP == 4) {
                        const float z = fmaxf(m + b2v[nt], 0.0f);
                        hw[(t2 * 4 + quad) * 68 + nt * 16 + col] = z;
                    } else {
                        m = fmaxf(m, __shfl_xor(m, 16));
                        const float z = fmaxf(m + b2v[nt], 0.0f);
                        if ((lane & 16) == 0)
                            hw[(t2 * 2 + (lane >> 5)) * 68 + nt * 16 + col] = z;
                    }
                }
            }
            if (t2 + 1 < TPW) {
                if (t2 + 2 < TPW) {
                    load_vrows<PT, KP, KREAL>(V, idxa, idxb, t2 + 2, lane, va);
                    load_urows<PT>(U, base16, t2 + 2, lane, ua);
                }
                f32x4 acc[4];
                stage_mfma<KSH>(base, lane, vb, ub, bh, bl, acc);
#pragma unroll
                for (int nt = 0; nt < 4; ++nt) {
                    float m = fmaxf(fmaxf(acc[nt].x, acc[nt].y), fmaxf(acc[nt].z, acc[nt].w));
                    if (KP == 4) {
                        const float z = fmaxf(m + b2v[nt], 0.0f);
                        hw[((t2 + 1) * 4 + quad) * 68 + nt * 16 + col] = z;
                    } else {
                        m = fmaxf(m, __shfl_xor(m, 16));
                        const float z = fmaxf(m + b2v[nt], 0.0f);
                        if ((lane & 16) == 0)
                            hw[((t2 + 1) * 2 + (lane >> 5)) * 68 + nt * 16 + col] = z;
                    }
                }
            }
        }
    }
    __builtin_amdgcn_wave_barrier();
    __builtin_amdgcn_s_waitcnt(0xc07f);   // h rows visible to this wave

    // ---- uv phase: [U'|V'] = h @ [W1n_a|W1n_b] ----------------------------
    v8s ah[2], al[2];
#pragma unroll
    for (int ks = 0; ks < 2; ++ks) {
        float w[8];
        const float4 f0 = *(const float4*)(hw + col * 68 + ks * 32 + quad * 8);
        const float4 f1 = *(const float4*)(hw + col * 68 + ks * 32 + quad * 8 + 4);
        w[0] = f0.x; w[1] = f0.y; w[2] = f0.z; w[3] = f0.w;
        w[4] = f1.x; w[5] = f1.y; w[6] = f1.z; w[7] = f1.w;
        pack8(w, ah[ks], al[ks]);
    }

    float prx[4], pry[4], prz[4];
#pragma unroll
    for (int r2 = 0; r2 < 4; ++r2) {
        const int pt = base16 + quad * 4 + r2;
        prx[r2] = pos[pt * 3 + 0];
        pry[r2] = pos[pt * 3 + 1];
        prz[r2] = pos[pt * 3 + 2];
    }
    float wcx[4], wcy[4], wcz[4], b1v[4];
#pragma unroll
    for (int nt = 0; nt < 4; ++nt) {
        wcx[nt] = W1n[128 * 64 + nt * 16 + col];
        wcy[nt] = W1n[129 * 64 + nt * 16 + col];
        wcz[nt] = W1n[130 * 64 + nt * 16 + col];
        b1v[nt] = b1n[nt * 16 + col];
    }

    for (int half = 1; half >= 0; --half) {
        v8s bh2[4][2], bl2[4][2];
#pragma unroll
        for (int nt = 0; nt < 4; ++nt) {
#pragma unroll
            for (int ks = 0; ks < 2; ++ks) {
                float w[8];
#pragma unroll
                for (int j = 0; j < 8; ++j)
                    w[j] = W1n[(size_t)(half * 64 + ks * 32 + quad * 8 + j) * 64 + nt * 16 + col];
                pack8(w, bh2[nt][ks], bl2[nt][ks]);
            }
        }

        f32x4 acc[4];
#pragma unroll
        for (int nt = 0; nt < 4; ++nt) acc[nt] = (f32x4){0.f, 0.f, 0.f, 0.f};
#pragma unroll
        for (int nt = 0; nt < 4; ++nt) {
#pragma unroll
            for (int ks = 0; ks < 2; ++ks) {
                acc[nt] = __builtin_amdgcn_mfma_f32_16x16x32_bf16(ah[ks], bh2[nt][ks], acc[nt], 0, 0, 0);
                acc[nt] = __builtin_amdgcn_mfma_f32_16x16x32_bf16(ah[ks], bl2[nt][ks], acc[nt], 0, 0, 0);
                acc[nt] = __builtin_amdgcn_mfma_f32_16x16x32_bf16(al[ks], bh2[nt][ks], acc[nt], 0, 0, 0);
            }
        }

        float* outp = half ? Vout : Uout;
#pragma unroll
        for (int nt = 0; nt < 4; ++nt) {
            const float* a = (const float*)&acc[nt];
#pragma unroll
            for (int r2 = 0; r2 < 4; ++r2) {
                float dotp = fmaf(prz[r2], wcz[nt], fmaf(pry[r2], wcy[nt], prx[r2] * wcx[nt]));
                float val = half ? (a[r2] + dotp) : (a[r2] + b1v[nt] - dotp);
                outp[(size_t)(base16 + quad * 4 + r2) * 64 + nt * 16 + col] = val;
            }
        }
    }
}

// ---------------------------------------------------------------------------
// Kernel 3: final edge layer, pipelined staging; pool-max in registers
// (round-1 verified form).
// ---------------------------------------------------------------------------
template <int PT, int KP, int KREAL, int TPW>
__global__ __launch_bounds__(256) void edge3_mfma_kernel(
    const float* __restrict__ U, const float* __restrict__ V,
    const int* __restrict__ idx,
    const float* __restrict__ W2, const float* __restrict__ b2,
    float* __restrict__ outp)
{
    __shared__ char ldsbuf[4 * 16 * 272];
    const int t = threadIdx.x;
    const int lane = t & 63;
    const int wv = __builtin_amdgcn_readfirstlane(t >> 6);
    char* base = &ldsbuf[wv * 16 * 272];
    const int col = lane & 15;
    const int quad = lane >> 4;
    constexpr int KSH = (KP == 8) ? 3 : 2;

    const int x = blockIdx.x & 7;
    const int r = blockIdx.x >> 3;
    const int g = x * 8 + (r & 7);
    const int sb = r >> 3;
    const int pbase = g * NP + (sb * 4 + wv) * (PT * TPW);   // 8 consecutive points

    const int idxa = idx[(size_t)pbase * 6 + lane];

    v8s bh[4][2], bl[4][2];
#pragma unroll
    for (int nt = 0; nt < 4; ++nt) {
#pragma unroll
        for (int ks = 0; ks < 2; ++ks) {
            float w[8];
#pragma unroll
            for (int j = 0; j < 8; ++j)
                w[j] = W2[(size_t)(ks * 32 + quad * 8 + j) * 64 + nt * 16 + col];
            pack8(w, bh[nt][ks], bl[nt][ks]);
        }
    }
    float b2v[4];
#pragma unroll
    for (int nt = 0; nt < 4; ++nt) b2v[nt] = b2[nt * 16 + col];

    float va[16], vb[16], ua[PT], ub[PT];
    load_vrows<PT, KP, KREAL>(V, idxa, idxa, 0, lane, va);
    load_urows<PT>(U, pbase, 0, lane, ua);

    float zacc[4] = {0.f, 0.f, 0.f, 0.f};

#pragma unroll
    for (int t2 = 0; t2 < TPW; t2 += 2) {
        if (t2 + 1 < TPW) {
            load_vrows<PT, KP, KREAL>(V, idxa, idxa, t2 + 1, lane, vb);
            load_urows<PT>(U, pbase, t2 + 1, lane, ub);
        }
        {
            f32x4 acc[4];
            stage_mfma<KSH>(base, lane, va, ua, bh, bl, acc);
#pragma unroll
            for (int nt = 0; nt < 4; ++nt) {
                float m = fmaxf(fmaxf(acc[nt].x, acc[nt].y), fmaxf(acc[nt].z, acc[nt].w));
                zacc[nt] = fmaxf(zacc[nt], fmaxf(m + b2v[nt], 0.0f));
            }
        }
        if (t2 + 1 < TPW) {
            if (t2 + 2 < TPW) {
                load_vrows<PT, KP, KREAL>(V, idxa, idxa, t2 + 2, lane, va);
                load_urows<PT>(U, pbase, t2 + 2, lane, ua);
            }
            f32x4 acc[4];
            stage_mfma<KSH>(base, lane, vb, ub, bh, bl, acc);
#pragma unroll
            for (int nt = 0; nt < 4; ++nt) {
                float m = fmaxf(fmaxf(acc[nt].x, acc[nt].y), fmaxf(acc[nt].z, acc[nt].w));
                zacc[nt] = fmaxf(zacc[nt], fmaxf(m + b2v[nt], 0.0f));
            }
        }
    }

#pragma unroll
    for (int nt = 0; nt < 4; ++nt) {
        float zm = fmaxf(zacc[nt], __shfl_xor(zacc[nt], 16));
        zm = fmaxf(zm, __shfl_xor(zm, 32));
        if (quad == 0) {
            atomicMax((unsigned int*)(outp + (size_t)g * 64 + nt * 16 + col),
                      __float_as_uint(zm));
        }
    }
}

// ---------------------------------------------------------------------------
// Kernel 4: final 64->6 regression from pooled. 6 blocks x 64 threads.
// ---------------------------------------------------------------------------
__global__ __launch_bounds__(64) void reg_kernel(
    const float* __restrict__ pooled, const float* __restrict__ regW,
    const float* __restrict__ regb, float* __restrict__ out)
{
    const int t = blockIdx.x * 64 + threadIdx.x;
    const int b = t / 6;
    const int o = t - b * 6;
    if (t < NB * 6) {
        float z = regb[o];
        const float* pb = pooled + (size_t)b * 64;
        for (int c = 0; c < 64; ++c) z = fmaf(pb[c], regW[c * 6 + o], z);
        out[b * 6 + o] = z;
    }
}

// ---------------------------------------------------------------------------
extern "C" void kernel_launch(void* const* d_in, const int* in_sizes, int n_in,
                              void* d_out, int out_size, void* d_ws, size_t ws_size,
                              hipStream_t stream)
{
    (void)in_sizes; (void)n_in; (void)out_size; (void)ws_size;
    const float* pos   = (const float*)d_in[1];
    const float* c1W1  = (const float*)d_in[3];
    const float* c1b1  = (const float*)d_in[4];
    const float* c1W2  = (const float*)d_in[5];
    const float* c1b2  = (const float*)d_in[6];
    const float* c2W1  = (const float*)d_in[7];
    const float* c2b1  = (const float*)d_in[8];
    const float* c2W2  = (const float*)d_in[9];
    const float* c2b2  = (const float*)d_in[10];
    const float* c3W1  = (const float*)d_in[11];
    const float* c3b1  = (const float*)d_in[12];
    const float* c3W2  = (const float*)d_in[13];
    const float* c3b2  = (const float*)d_in[14];
    const float* regW  = (const float*)d_in[15];
    const float* regb  = (const float*)d_in[16];
    float* out = (float*)d_out;

    // workspace: idx | A | C | D | E | pooled  (A,C,D,E are 65536x64 fp32)
    char* ws = (char*)d_ws;
    int*   idx = (int*)ws;                                    // 1.5 MB
    float* A = (float*)(ws + 1572864);
    float* C = (float*)(ws + 1572864 + 1 * 16777216);
    float* D = (float*)(ws + 1572864 + 2 * 16777216);
    float* E = (float*)(ws + 1572864 + 3 * 16777216);
    float* pooled = (float*)(ws + 1572864 + 4 * 16777216);    // 16 KB

    // kNN + fused layer-1 prep (U1 -> D, Vpos -> C) in one launch
    knn6_prep_kernel<<<NB * 16, 256, 0, stream>>>(pos, c1W1, c1b1, idx, D, C);

    // fused layer1-edge + layer2-uv: reads (D=U1, C=Vpos) -> U2->A, V2->E
    fused_edge_uv_kernel<2, 8, 6><<<1024, 256, 0, stream>>>(
        D, C, idx, c1W2, c1b2, c2W1, c2b1, pos, A, E, nullptr);

    // fused layer2-edge + layer3-uv: reads (A=U2, E=V2) -> U3->D, V3->C
    // (block 0 zeroes pooled)
    fused_edge_uv_kernel<4, 4, 4><<<1024, 256, 0, stream>>>(
        A, E, idx, c2W2, c2b2, c3W1, c3b1, pos, D, C, pooled);

    // layer3 edge -> atomic max into pooled
    edge3_mfma_kernel<4, 4, 3, 2><<<2048, 256, 0, stream>>>(
        D, C, idx, c3W2, c3b2, pooled);

    // final regression
    reg_kernel<<<6, 64, 0, stream>>>(pooled, regW, regb, out);
}